// Round 1
// baseline (946.767 us; speedup 1.0000x reference)
//
#include <hip/hip_runtime.h>
#include <hip/hip_bf16.h>
#include <math.h>

#define L_SEQ 2048
#define S_SEQ 2048
#define N_B 2
#define E_DIM 512
#define H_HEADS 8
#define D_HEAD 64
#define M_ROWS (L_SEQ * N_B)    // 4096 rows for the projection GEMMs
#define BH (H_HEADS * N_B)      // 16 attention batches (h*N + n)

// ---------------------------------------------------------------------------
// Projection GEMM: Y = X @ W^T + b
//   X: (M_ROWS, E_DIM) row-major (this is exactly the (L,N,E)/(S,N,E) flat layout)
//   W: (E_DIM, E_DIM) row-major (out_features, in_features)  -> B[k][n] = W[n][k]
// QKV=true : scatter output to per-(n,h) matrices: out[((n*H+h)*L + l)*D + d]
// QKV=false: plain row-major out[r*E + e]  (final output projection)
// 64x64 tile, BK=16, 256 threads, 4x4 micro-tile per thread.
// ---------------------------------------------------------------------------
template <bool QKV>
__global__ void proj_kernel(const float* __restrict__ X, const float* __restrict__ W,
                            const float* __restrict__ b, float* __restrict__ out) {
    __shared__ float As[16][65];   // [k][m]  (+1 pad: stride 65 breaks bank aliasing)
    __shared__ float Bs[16][65];   // [k][n]
    const int bm = blockIdx.y * 64;
    const int bn = blockIdx.x * 64;
    const int tid = threadIdx.x;
    const int tm = (tid >> 4) << 2;   // 0..60
    const int tn = (tid & 15) << 2;   // 0..60

    float acc[4][4] = {};

    for (int k0 = 0; k0 < E_DIM; k0 += 16) {
#pragma unroll
        for (int i = 0; i < 4; ++i) {
            const int idx = tid + i * 256;          // 0..1023
            const int row = idx >> 4;               // 0..63
            const int kk  = idx & 15;               // 0..15
            As[kk][row] = X[(size_t)(bm + row) * E_DIM + (k0 + kk)];
            Bs[kk][row] = W[(size_t)(bn + row) * E_DIM + (k0 + kk)];
        }
        __syncthreads();
#pragma unroll
        for (int kk = 0; kk < 16; ++kk) {
            float a[4], bb[4];
#pragma unroll
            for (int i = 0; i < 4; ++i) a[i] = As[kk][tm + i];
#pragma unroll
            for (int j = 0; j < 4; ++j) bb[j] = Bs[kk][tn + j];
#pragma unroll
            for (int i = 0; i < 4; ++i)
#pragma unroll
                for (int j = 0; j < 4; ++j) acc[i][j] += a[i] * bb[j];
        }
        __syncthreads();
    }

#pragma unroll
    for (int i = 0; i < 4; ++i) {
        const int r = bm + tm + i;
        const int l = r >> 1;           // N_B == 2
        const int n = r & 1;
#pragma unroll
        for (int j = 0; j < 4; ++j) {
            const int e = bn + tn + j;
            const float v = acc[i][j] + b[e];
            if (QKV) {
                const int h = e >> 6;   // D_HEAD == 64
                const int d = e & 63;
                out[((size_t)(n * H_HEADS + h) * L_SEQ + l) * D_HEAD + d] = v;
            } else {
                out[(size_t)r * E_DIM + e] = v;
            }
        }
    }
}

// ---------------------------------------------------------------------------
// Scores: for batch bh=(h*N+n): scores[l][s] = 0.125 * Q[l]·K[s] + bias[l][s]
// Q,K stored per-(n,h) as (L,D)/(S,D). Writes directly into the attn_weights
// output region (softmax'd in place afterwards).
// ---------------------------------------------------------------------------
__global__ void scores_kernel(const float* __restrict__ Qb, const float* __restrict__ Kb,
                              const float* __restrict__ bias, float* __restrict__ wout) {
    const int bh = blockIdx.z;
    const int h = bh / N_B;
    const int n = bh % N_B;
    const float* __restrict__ Q = Qb + (size_t)(n * H_HEADS + h) * L_SEQ * D_HEAD;
    const float* __restrict__ K = Kb + (size_t)(n * H_HEADS + h) * S_SEQ * D_HEAD;
    float* __restrict__ out = wout + (size_t)bh * L_SEQ * S_SEQ;

    __shared__ float As[16][65];   // [k][l]
    __shared__ float Bs[16][65];   // [k][s]
    const int bl = blockIdx.y * 64;
    const int bs = blockIdx.x * 64;
    const int tid = threadIdx.x;
    const int tm = (tid >> 4) << 2;
    const int tn = (tid & 15) << 2;

    float acc[4][4] = {};

    for (int k0 = 0; k0 < D_HEAD; k0 += 16) {
#pragma unroll
        for (int i = 0; i < 4; ++i) {
            const int idx = tid + i * 256;
            const int row = idx >> 4;
            const int kk  = idx & 15;
            As[kk][row] = Q[(size_t)(bl + row) * D_HEAD + (k0 + kk)];
            Bs[kk][row] = K[(size_t)(bs + row) * D_HEAD + (k0 + kk)];
        }
        __syncthreads();
#pragma unroll
        for (int kk = 0; kk < 16; ++kk) {
            float a[4], bb[4];
#pragma unroll
            for (int i = 0; i < 4; ++i) a[i] = As[kk][tm + i];
#pragma unroll
            for (int j = 0; j < 4; ++j) bb[j] = Bs[kk][tn + j];
#pragma unroll
            for (int i = 0; i < 4; ++i)
#pragma unroll
                for (int j = 0; j < 4; ++j) acc[i][j] += a[i] * bb[j];
        }
        __syncthreads();
    }

#pragma unroll
    for (int i = 0; i < 4; ++i) {
        const int l = bl + tm + i;
#pragma unroll
        for (int j = 0; j < 4; ++j) {
            const int s = bs + tn + j;
            out[(size_t)l * S_SEQ + s] = acc[i][j] * 0.125f + bias[(size_t)l * S_SEQ + s];
        }
    }
}

// ---------------------------------------------------------------------------
// Row softmax in place over the last dim (S=2048). One block per row.
// ---------------------------------------------------------------------------
__global__ void softmax_kernel(float* __restrict__ w) {
    float* __restrict__ row = w + (size_t)blockIdx.x * S_SEQ;
    const int tid = threadIdx.x;

    float vals[8];
    float m = -INFINITY;
#pragma unroll
    for (int i = 0; i < 8; ++i) {
        vals[i] = row[tid + i * 256];
        m = fmaxf(m, vals[i]);
    }
    __shared__ float red[256];
    red[tid] = m;
    __syncthreads();
    for (int off = 128; off > 0; off >>= 1) {
        if (tid < off) red[tid] = fmaxf(red[tid], red[tid + off]);
        __syncthreads();
    }
    m = red[0];
    __syncthreads();

    float sum = 0.f;
#pragma unroll
    for (int i = 0; i < 8; ++i) {
        vals[i] = __expf(vals[i] - m);
        sum += vals[i];
    }
    red[tid] = sum;
    __syncthreads();
    for (int off = 128; off > 0; off >>= 1) {
        if (tid < off) red[tid] += red[tid + off];
        __syncthreads();
    }
    const float inv = 1.0f / red[0];
#pragma unroll
    for (int i = 0; i < 8; ++i) row[tid + i * 256] = vals[i] * inv;
}

// ---------------------------------------------------------------------------
// PV: ctx[l][n][h*D+d] = sum_s Wgt[bh][l][s] * V[(n,h)][s][d]
// Writes ctx in plain (L*N, E) row-major so the output projection can reuse
// the plain GEMM.
// ---------------------------------------------------------------------------
__global__ void pv_kernel(const float* __restrict__ wgt, const float* __restrict__ Vb,
                          float* __restrict__ ctx) {
    const int bh = blockIdx.z;
    const int h = bh / N_B;
    const int n = bh % N_B;
    const float* __restrict__ Wm = wgt + (size_t)bh * L_SEQ * S_SEQ;
    const float* __restrict__ V = Vb + (size_t)(n * H_HEADS + h) * S_SEQ * D_HEAD;

    __shared__ float As[16][65];   // [k][l]
    __shared__ float Bs[16][65];   // [k][d]
    const int bl = blockIdx.y * 64;
    const int tid = threadIdx.x;
    const int tm = (tid >> 4) << 2;
    const int tn = (tid & 15) << 2;

    float acc[4][4] = {};

    for (int k0 = 0; k0 < S_SEQ; k0 += 16) {
#pragma unroll
        for (int i = 0; i < 4; ++i) {
            const int idx = tid + i * 256;
            // A: 64 rows x 16 k
            const int arow = idx >> 4;
            const int akk  = idx & 15;
            As[akk][arow] = Wm[(size_t)(bl + arow) * S_SEQ + (k0 + akk)];
            // B: 16 k x 64 d (coalesced over d)
            const int bkk = idx >> 6;
            const int bd  = idx & 63;
            Bs[bkk][bd] = V[(size_t)(k0 + bkk) * D_HEAD + bd];
        }
        __syncthreads();
#pragma unroll
        for (int kk = 0; kk < 16; ++kk) {
            float a[4], bb[4];
#pragma unroll
            for (int i = 0; i < 4; ++i) a[i] = As[kk][tm + i];
#pragma unroll
            for (int j = 0; j < 4; ++j) bb[j] = Bs[kk][tn + j];
#pragma unroll
            for (int i = 0; i < 4; ++i)
#pragma unroll
                for (int j = 0; j < 4; ++j) acc[i][j] += a[i] * bb[j];
        }
        __syncthreads();
    }

#pragma unroll
    for (int i = 0; i < 4; ++i) {
        const int l = bl + tm + i;
#pragma unroll
        for (int j = 0; j < 4; ++j) {
            const int d = tn + j;
            ctx[((size_t)l * N_B + n) * E_DIM + h * D_HEAD + d] = acc[i][j];
        }
    }
}

extern "C" void kernel_launch(void* const* d_in, const int* in_sizes, int n_in,
                              void* d_out, int out_size, void* d_ws, size_t ws_size,
                              hipStream_t stream) {
    const float* query = (const float*)d_in[0];
    const float* key   = (const float*)d_in[1];
    const float* value = (const float*)d_in[2];
    const float* bias  = (const float*)d_in[3];
    const float* Wq    = (const float*)d_in[4];
    const float* bq    = (const float*)d_in[5];
    const float* Wk    = (const float*)d_in[6];
    const float* bk    = (const float*)d_in[7];
    const float* Wv    = (const float*)d_in[8];
    const float* bv    = (const float*)d_in[9];
    const float* Wo    = (const float*)d_in[10];
    const float* bo    = (const float*)d_in[11];

    float* out0 = (float*)d_out;                              // attn_out (L,N,E)
    float* wgt  = out0 + (size_t)M_ROWS * E_DIM;              // attn_weights (BH,L,S)

    float* ws = (float*)d_ws;
    const size_t buf = (size_t)M_ROWS * E_DIM;                // 2M floats = 8 MB
    float* Qb  = ws;            // (N*H, L, D)
    float* Kb  = ws + buf;      // (N*H, S, D)
    float* Vb  = ws + 2 * buf;  // (N*H, S, D)
    float* ctx = ws + 3 * buf;  // (L*N, E) plain

    const dim3 blk(256);
    const dim3 gproj(E_DIM / 64, M_ROWS / 64);
    proj_kernel<true><<<gproj, blk, 0, stream>>>(query, Wq, bq, Qb);
    proj_kernel<true><<<gproj, blk, 0, stream>>>(key,   Wk, bk, Kb);
    proj_kernel<true><<<gproj, blk, 0, stream>>>(value, Wv, bv, Vb);

    const dim3 gsc(S_SEQ / 64, L_SEQ / 64, BH);
    scores_kernel<<<gsc, blk, 0, stream>>>(Qb, Kb, bias, wgt);

    softmax_kernel<<<dim3(BH * L_SEQ), blk, 0, stream>>>(wgt);

    const dim3 gpv(1, L_SEQ / 64, BH);
    pv_kernel<<<gpv, blk, 0, stream>>>(wgt, Vb, ctx);

    proj_kernel<false><<<gproj, blk, 0, stream>>>(ctx, Wo, bo, out0);
}

// Round 3
// 568.653 us; speedup vs baseline: 1.6649x; 1.6649x over previous
//
#include <hip/hip_runtime.h>
#include <hip/hip_bf16.h>
#include <math.h>

#define L_SEQ 2048
#define S_SEQ 2048
#define N_B 2
#define E_DIM 512
#define H_HEADS 8
#define D_HEAD 64
#define M_ROWS (L_SEQ * N_B)
#define BH (H_HEADS * N_B)   // batch index = h*N_B + n (matches attn_weights reshape (H*N, L, S))

typedef __attribute__((ext_vector_type(8))) short bf16x8;
typedef __attribute__((ext_vector_type(4))) float f32x4;

#define MFMA(a, b, c) __builtin_amdgcn_mfma_f32_16x16x32_bf16((a), (b), (c), 0, 0, 0)
// Verified layouts (learn_hip m89/m91):
//   A-frag: A[m = lane&15][k = (lane>>4)*8 + j]   (8 contiguous k per lane)
//   B-frag: B[k = (lane>>4)*8 + j][n = lane&15]   (read from row-major Bt[n][k])
//   C/D   : col = lane&15, row = (lane>>4)*4 + reg

__device__ __forceinline__ short f2bf(float v) {
    union { __hip_bfloat16 h; short s; } u;
    u.h = __float2bfloat16(v);
    return u.s;
}
__device__ __forceinline__ float bf2f(short s) {
    union { __hip_bfloat16 h; short t; } u;
    u.t = s;
    return __bfloat162float(u.h);
}
__device__ __forceinline__ void cvt8_hl(const float4& a, const float4& b, bf16x8& h, bf16x8& l) {
    float v[8] = {a.x, a.y, a.z, a.w, b.x, b.y, b.z, b.w};
#pragma unroll
    for (int i = 0; i < 8; ++i) {
        short hh = f2bf(v[i]);
        h[i] = hh;
        l[i] = f2bf(v[i] - bf2f(hh));
    }
}
__device__ __forceinline__ bf16x8 cvt8_h(const float4& a, const float4& b) {
    float v[8] = {a.x, a.y, a.z, a.w, b.x, b.y, b.z, b.w};
    bf16x8 h;
#pragma unroll
    for (int i = 0; i < 8; ++i) h[i] = f2bf(v[i]);
    return h;
}

// ---------------------------------------------------------------------------
// Deterministic workspace init: zero the 28 MB of d_ws we use so every launch
// starts from identical state regardless of harness poison.
// ---------------------------------------------------------------------------
__global__ __launch_bounds__(256) void fill_kernel(float4* __restrict__ p, int n4) {
    const float4 z = {0.f, 0.f, 0.f, 0.f};
    for (int i = blockIdx.x * 256 + threadIdx.x; i < n4; i += gridDim.x * 256) p[i] = z;
}

// ---------------------------------------------------------------------------
// QKV projection: Y = X @ W^T + b, split-bf16 (hi/lo) MFMA for ~fp32 accuracy.
// Output: per-batch [bh = h*2+n][seq][64] bf16 hi and lo (lo of V is dumped
// into a scratch buffer that is fully overwritten later).
// 64x64 tile, 256 threads (4 waves). LDS row stride 40 shorts: 16B-aligned,
// only 2-way bank alias (free per m136).
// ---------------------------------------------------------------------------
__global__ __launch_bounds__(256) void proj_qkv_kernel(
    const float* __restrict__ X, const float* __restrict__ W,
    const float* __restrict__ bias, short* __restrict__ outH, short* __restrict__ outL) {
    __shared__ __align__(16) short Ah[64 * 40], Al[64 * 40], Bh[64 * 40], Bl[64 * 40];
    const int bn = blockIdx.x * 64;
    const int bm = blockIdx.y * 64;
    const int tid = threadIdx.x;
    const int wave = tid >> 6, lane = tid & 63;
    const int m16 = lane & 15, q = lane >> 4;
    const int srow = tid >> 2, sk = (tid & 3) * 8;

    f32x4 acc[4] = {};

    for (int k0 = 0; k0 < E_DIM; k0 += 32) {
        {
            const float4* pa = (const float4*)(X + (size_t)(bm + srow) * E_DIM + k0 + sk);
            float4 a0 = pa[0], a1 = pa[1];
            const float4* pb = (const float4*)(W + (size_t)(bn + srow) * E_DIM + k0 + sk);
            float4 b0 = pb[0], b1 = pb[1];
            bf16x8 vh, vl;
            cvt8_hl(a0, a1, vh, vl);
            *(bf16x8*)&Ah[srow * 40 + sk] = vh;
            *(bf16x8*)&Al[srow * 40 + sk] = vl;
            cvt8_hl(b0, b1, vh, vl);
            *(bf16x8*)&Bh[srow * 40 + sk] = vh;
            *(bf16x8*)&Bl[srow * 40 + sk] = vl;
        }
        __syncthreads();
        const bf16x8 ah = *(const bf16x8*)&Ah[(wave * 16 + m16) * 40 + q * 8];
        const bf16x8 al = *(const bf16x8*)&Al[(wave * 16 + m16) * 40 + q * 8];
#pragma unroll
        for (int j = 0; j < 4; ++j) {
            const bf16x8 bh_ = *(const bf16x8*)&Bh[(j * 16 + m16) * 40 + q * 8];
            const bf16x8 bl_ = *(const bf16x8*)&Bl[(j * 16 + m16) * 40 + q * 8];
            acc[j] = MFMA(ah, bh_, acc[j]);
            acc[j] = MFMA(ah, bl_, acc[j]);
            acc[j] = MFMA(al, bh_, acc[j]);
        }
        __syncthreads();
    }

#pragma unroll
    for (int j = 0; j < 4; ++j) {
        const int e = bn + j * 16 + m16;
        const int h = e >> 6, d = e & 63;
        const float be = bias[e];
#pragma unroll
        for (int r = 0; r < 4; ++r) {
            const int row = bm + wave * 16 + q * 4 + r;
            const int l = row >> 1, n = row & 1;
            const float v = acc[j][r] + be;
            const size_t idx = ((size_t)(h * 2 + n) * L_SEQ + l) * D_HEAD + d;
            const short hi = f2bf(v);
            outH[idx] = hi;
            outL[idx] = f2bf(v - bf2f(hi));
        }
    }
}

// ---------------------------------------------------------------------------
// V transpose: Vb [bh][s][64] bf16 -> Vt [bh][64][s] bf16 (k-contiguous B-frags)
// ---------------------------------------------------------------------------
__global__ __launch_bounds__(256) void vtrans_kernel(const short* __restrict__ Vb,
                                                     short* __restrict__ Vt) {
    __shared__ short tile[64][65];
    const int s0 = blockIdx.x * 64;
    const int bh = blockIdx.y;
    const int t = threadIdx.x;
    const int r = t >> 2, seg = (t & 3) * 16;
    const bf16x8* p = (const bf16x8*)(Vb + ((size_t)bh * S_SEQ + s0 + r) * D_HEAD + seg);
    bf16x8 v0 = p[0], v1 = p[1];
#pragma unroll
    for (int i = 0; i < 8; ++i) {
        tile[r][seg + i] = v0[i];
        tile[r][seg + 8 + i] = v1[i];
    }
    __syncthreads();
    bf16x8 o0, o1;
#pragma unroll
    for (int i = 0; i < 8; ++i) {
        o0[i] = tile[seg + i][r];
        o1[i] = tile[seg + 8 + i][r];
    }
    bf16x8* po = (bf16x8*)(Vt + ((size_t)bh * D_HEAD + r) * S_SEQ + s0 + seg);
    po[0] = o0;
    po[1] = o1;
}

// ---------------------------------------------------------------------------
// Fused scores + bias + softmax + PV. Block = (bh, 16 L-rows), 512 thr = 8 waves.
// Wave w covers s in [w*256, w*256+256). Phase 1: split-bf16 QK^T (3 MFMAs),
// exact softmax (quad shfl butterfly + LDS cross-wave), write fp32 weights
// (d_out is write-only). Phase 2: P (registers, C-layout) -> LDS transpose ->
// A-frags -> MFMA vs Vt. Phase 3: cross-wave partial-O reduce in LDS -> ctx bf16.
// ---------------------------------------------------------------------------
__global__ __launch_bounds__(512) void scores_pv_kernel(
    const short* __restrict__ Qh, const short* __restrict__ Ql,
    const short* __restrict__ Kh, const short* __restrict__ Kl,
    const short* __restrict__ Vt, const float* __restrict__ bias,
    float* __restrict__ wout, short* __restrict__ ctx) {
    const int bh = blockIdx.y;
    const int l0 = blockIdx.x * 16;
    const int tid = threadIdx.x;
    const int wave = tid >> 6, lane = tid & 63;
    const int m16 = lane & 15, q = lane >> 4;
    const int sbase = wave * 256;

    __shared__ float LMAX[8][16], LSUM[8][16];
    __shared__ __align__(16) float SM_T[8][32][17];   // per-wave P transpose tile
    __shared__ __align__(16) float OB[8][16][65];     // partial O per wave

    // ---- Phase 1: QK^T + bias ----
    const size_t qoff = ((size_t)bh * L_SEQ + l0 + m16) * D_HEAD;
    bf16x8 aH[2], aL[2];
#pragma unroll
    for (int ks = 0; ks < 2; ++ks) {
        aH[ks] = *(const bf16x8*)(Qh + qoff + ks * 32 + q * 8);
        aL[ks] = *(const bf16x8*)(Ql + qoff + ks * 32 + q * 8);
    }

    f32x4 C[16] = {};
#pragma unroll
    for (int t = 0; t < 16; ++t) {
        const size_t koff = ((size_t)bh * S_SEQ + sbase + t * 16 + m16) * D_HEAD;
#pragma unroll
        for (int ks = 0; ks < 2; ++ks) {
            const bf16x8 kh = *(const bf16x8*)(Kh + koff + ks * 32 + q * 8);
            const bf16x8 kl = *(const bf16x8*)(Kl + koff + ks * 32 + q * 8);
            C[t] = MFMA(aH[ks], kh, C[t]);
            C[t] = MFMA(aH[ks], kl, C[t]);
            C[t] = MFMA(aL[ks], kh, C[t]);
        }
    }

    const int row0 = l0 + q * 4;
#pragma unroll
    for (int r = 0; r < 4; ++r) {
        const float* brow = bias + (size_t)(row0 + r) * S_SEQ + sbase + m16;
#pragma unroll
        for (int t = 0; t < 16; ++t) C[t][r] = C[t][r] * 0.125f + brow[t * 16];
    }

    // ---- softmax (exact, 2-pass over registers) ----
    float mx[4] = {-INFINITY, -INFINITY, -INFINITY, -INFINITY};
#pragma unroll
    for (int t = 0; t < 16; ++t)
#pragma unroll
        for (int r = 0; r < 4; ++r) mx[r] = fmaxf(mx[r], C[t][r]);
#pragma unroll
    for (int d = 1; d < 16; d <<= 1)
#pragma unroll
        for (int r = 0; r < 4; ++r) mx[r] = fmaxf(mx[r], __shfl_xor(mx[r], d, 64));
    if (m16 == 0) {
#pragma unroll
        for (int r = 0; r < 4; ++r) LMAX[wave][q * 4 + r] = mx[r];
    }
    __syncthreads();
    float M[4];
#pragma unroll
    for (int r = 0; r < 4; ++r) {
        float v = -INFINITY;
#pragma unroll
        for (int w = 0; w < 8; ++w) v = fmaxf(v, LMAX[w][q * 4 + r]);
        M[r] = v;
    }

    float sm[4] = {};
#pragma unroll
    for (int t = 0; t < 16; ++t)
#pragma unroll
        for (int r = 0; r < 4; ++r) {
            const float e = __expf(C[t][r] - M[r]);
            C[t][r] = e;
            sm[r] += e;
        }
#pragma unroll
    for (int d = 1; d < 16; d <<= 1)
#pragma unroll
        for (int r = 0; r < 4; ++r) sm[r] += __shfl_xor(sm[r], d, 64);
    if (m16 == 0) {
#pragma unroll
        for (int r = 0; r < 4; ++r) LSUM[wave][q * 4 + r] = sm[r];
    }
    __syncthreads();
#pragma unroll
    for (int r = 0; r < 4; ++r) {
        float s = 0.f;
#pragma unroll
        for (int w = 0; w < 8; ++w) s += LSUM[w][q * 4 + r];
        const float inv = 1.0f / s;
        float* orow = wout + ((size_t)bh * L_SEQ + row0 + r) * S_SEQ + sbase + m16;
#pragma unroll
        for (int t = 0; t < 16; ++t) {
            C[t][r] *= inv;
            orow[t * 16] = C[t][r];
        }
    }

    // ---- Phase 2: O = P @ V (per-wave strip), P via LDS transpose ----
    f32x4 O[4] = {};
    float (*T)[17] = SM_T[wave];
    for (int c = 0; c < 8; ++c) {
        __syncthreads();   // WAR: previous iteration's reads of T complete
#pragma unroll
        for (int r = 0; r < 4; ++r) {
            T[m16][q * 4 + r]      = C[2 * c][r];
            T[16 + m16][q * 4 + r] = C[2 * c + 1][r];
        }
        __syncthreads();
        bf16x8 a;
#pragma unroll
        for (int j = 0; j < 8; ++j) a[j] = f2bf(T[q * 8 + j][m16]);
        const int scol = sbase + c * 32;
#pragma unroll
        for (int j = 0; j < 4; ++j) {
            const bf16x8 b =
                *(const bf16x8*)(Vt + ((size_t)bh * D_HEAD + j * 16 + m16) * S_SEQ + scol + q * 8);
            O[j] = MFMA(a, b, O[j]);
        }
    }

    // ---- Phase 3: reduce partial O across waves, write ctx ----
    __syncthreads();
#pragma unroll
    for (int j = 0; j < 4; ++j)
#pragma unroll
        for (int r = 0; r < 4; ++r) OB[wave][q * 4 + r][j * 16 + m16] = O[j][r];
    __syncthreads();

    const int h = bh >> 1, n = bh & 1;
#pragma unroll
    for (int u = 0; u < 2; ++u) {
        const int idx = tid + u * 512;        // 0..1023 = 16 rows x 64 d
        const int row = idx >> 6, d = idx & 63;
        float s = 0.f;
#pragma unroll
        for (int w = 0; w < 8; ++w) s += OB[w][row][d];
        ctx[(size_t)((l0 + row) * N_B + n) * E_DIM + h * D_HEAD + d] = f2bf(s);
    }
}

// ---------------------------------------------------------------------------
// Output projection: out = ctx(bf16) @ Wo^T + bo, fp32 out.
// ---------------------------------------------------------------------------
__global__ __launch_bounds__(256) void oproj_kernel(const short* __restrict__ ctx,
                                                    const float* __restrict__ W,
                                                    const float* __restrict__ bias,
                                                    float* __restrict__ out) {
    __shared__ __align__(16) short Bh[64 * 40];
    const int bn = blockIdx.x * 64;
    const int bm = blockIdx.y * 64;
    const int tid = threadIdx.x;
    const int wave = tid >> 6, lane = tid & 63;
    const int m16 = lane & 15, q = lane >> 4;
    const int srow = tid >> 2, sk = (tid & 3) * 8;

    f32x4 acc[4] = {};
    for (int k0 = 0; k0 < E_DIM; k0 += 32) {
        {
            const float4* pb = (const float4*)(W + (size_t)(bn + srow) * E_DIM + k0 + sk);
            *(bf16x8*)&Bh[srow * 40 + sk] = cvt8_h(pb[0], pb[1]);
        }
        __syncthreads();
        const bf16x8 a = *(const bf16x8*)(ctx + (size_t)(bm + wave * 16 + m16) * E_DIM + k0 + q * 8);
#pragma unroll
        for (int j = 0; j < 4; ++j) {
            const bf16x8 b = *(const bf16x8*)&Bh[(j * 16 + m16) * 40 + q * 8];
            acc[j] = MFMA(a, b, acc[j]);
        }
        __syncthreads();
    }
#pragma unroll
    for (int j = 0; j < 4; ++j) {
        const int e = bn + j * 16 + m16;
        const float be = bias[e];
#pragma unroll
        for (int r = 0; r < 4; ++r)
            out[(size_t)(bm + wave * 16 + q * 4 + r) * E_DIM + e] = acc[j][r] + be;
    }
}

extern "C" void kernel_launch(void* const* d_in, const int* in_sizes, int n_in,
                              void* d_out, int out_size, void* d_ws, size_t ws_size,
                              hipStream_t stream) {
    const float* query = (const float*)d_in[0];
    const float* key   = (const float*)d_in[1];
    const float* value = (const float*)d_in[2];
    const float* bias  = (const float*)d_in[3];
    const float* Wq    = (const float*)d_in[4];
    const float* bq    = (const float*)d_in[5];
    const float* Wk    = (const float*)d_in[6];
    const float* bk    = (const float*)d_in[7];
    const float* Wv    = (const float*)d_in[8];
    const float* bv    = (const float*)d_in[9];
    const float* Wo    = (const float*)d_in[10];
    const float* bo    = (const float*)d_in[11];

    float* out0 = (float*)d_out;                       // attn_out (L,N,E) — write-only
    float* wgt  = out0 + (size_t)M_ROWS * E_DIM;       // attn_weights (BH,L,S) fp32 — write-only

    // ws: 7 x 4 MB bf16 buffers = 28 MB
    short* wsS = (short*)d_ws;
    const size_t buf = (size_t)BH * L_SEQ * D_HEAD;    // 2,097,152 elems
    short* Qh  = wsS + 0 * buf;
    short* Ql  = wsS + 1 * buf;
    short* Kh  = wsS + 2 * buf;
    short* Kl  = wsS + 3 * buf;
    short* Vh  = wsS + 4 * buf;
    short* Vt  = wsS + 5 * buf;
    short* ctx = wsS + 6 * buf;

    // Deterministic ws baseline every call (28 MB = 1,835,008 float4)
    fill_kernel<<<2048, 256, 0, stream>>>((float4*)d_ws, (int)(7 * buf * sizeof(short) / 16));

    const dim3 gproj(E_DIM / 64, M_ROWS / 64);         // (8, 64)
    proj_qkv_kernel<<<gproj, 256, 0, stream>>>(query, Wq, bq, Qh, Ql);
    proj_qkv_kernel<<<gproj, 256, 0, stream>>>(key, Wk, bk, Kh, Kl);
    // V's lo-correction is not consumed; dump it into ctx (fully overwritten below).
    proj_qkv_kernel<<<gproj, 256, 0, stream>>>(value, Wv, bv, Vh, ctx);

    vtrans_kernel<<<dim3(S_SEQ / 64, BH), 256, 0, stream>>>(Vh, Vt);

    scores_pv_kernel<<<dim3(L_SEQ / 16, BH), 512, 0, stream>>>(Qh, Ql, Kh, Kl, Vt, bias, wgt, ctx);

    oproj_kernel<<<gproj, 256, 0, stream>>>(ctx, Wo, bo, out0);
}